// Round 4
// baseline (103.985 us; speedup 1.0000x reference)
//
#include <hip/hip_runtime.h>
#include <hip/hip_bf16.h>
#include <math.h>

// NTXent loss, N=8192 rows, D=128.
// loss = mean_i [ log(sum_{j!=i} exp(2*cos_ij)) - 2*cos_{i,partner} ]
// R3: symmetry — compute upper-triangle 256x256 tiles only; each exp feeds
// row-sum (register) AND col-sum (LDS -> 1 atomic/col/block). MFMA work
// halves (8.3 -> 4.3 us floor). zn pre-scaled by sqrt(2/ln2) so the exp
// is exp2(acc) with no per-element multiply.

typedef __attribute__((ext_vector_type(8))) short bf16x8;   // 8 bf16 = 4 VGPRs
typedef __attribute__((ext_vector_type(4))) float f32x4;

#define NROWS 8192
#define DDIM  128
#define BHALF 4096
#define CHUNK 32                    // sim-cols per LDS chunk
// zn scaled by sqrt(2/ln2): acc = (2/ln2)*cos, exp(2cos) = exp2(acc)
#define SQRT_E2S 1.6986435980707531f
#define TWO_LN2  1.3862943611198906f

static __device__ __forceinline__ unsigned short f2bf(float f) {
  unsigned int u = __float_as_uint(f);
  unsigned int r = (u + 0x7fffu + ((u >> 16) & 1u)) >> 16;   // RNE
  return (unsigned short)r;
}

static __device__ __forceinline__ void glds16(const unsigned short* g, unsigned short* l) {
  // lane i writes LDS at (wave-uniform l) + lane*16B; per-lane global addr g.
  __builtin_amdgcn_global_load_lds((const __attribute__((address_space(1))) unsigned int*)g,
                                   (__attribute__((address_space(3))) unsigned int*)l,
                                   16, 0, 0);
}

// ---- Kernel 1: row-normalize (scaled) into bf16, zero row_sums and out ---
__global__ void norm_zero_kernel(const float* __restrict__ zi, const float* __restrict__ zj,
                                 unsigned short* __restrict__ zn,
                                 float* __restrict__ row_sums, float* __restrict__ out) {
  int wave = threadIdx.x >> 6;
  int lane = threadIdx.x & 63;
  int row  = blockIdx.x * 4 + wave;                 // grid 2048 * 4 waves = 8192 rows
  const float* src = (row < BHALF) ? (zi + (size_t)row * DDIM)
                                   : (zj + (size_t)(row - BHALF) * DDIM);
  float2 v = *(const float2*)(src + 2 * lane);
  float ss = v.x * v.x + v.y * v.y;
  #pragma unroll
  for (int off = 1; off < 64; off <<= 1) ss += __shfl_xor(ss, off);
  float scale = SQRT_E2S / fmaxf(sqrtf(ss), 1e-8f);
  unsigned int lo = f2bf(v.x * scale);
  unsigned int hi = f2bf(v.y * scale);
  ((unsigned int*)(zn + (size_t)row * DDIM))[lane] = lo | (hi << 16);

  if (threadIdx.x < 4) row_sums[blockIdx.x * 4 + threadIdx.x] = 0.0f;
  if (blockIdx.x == 0 && threadIdx.x == 0) out[0] = 0.0f;
}

// ---- Kernel 2: fused sim + exp + row/col sums (upper triangle) -----------
// Grid (32,32); blocks with y<x exit. Tile 256x256. Block = 4 waves, 64
// rows/wave, A in registers; B in 32-col chunks double-buffered via
// global_load_lds (XOR 16B-chunk swizzle -> conflict-free ds_read_b128).
__global__ __launch_bounds__(256, 2)
void sim_kernel(const unsigned short* __restrict__ zn, float* __restrict__ row_sums) {
  if (blockIdx.y < blockIdx.x) return;               // lower triangle: skip
  const bool diag = (blockIdx.x == blockIdx.y);

  __shared__ unsigned short lds[2 * CHUNK * DDIM];   // 2 x 8 KB
  __shared__ float colsum[256];

  const int wave = threadIdx.x >> 6;
  const int lane = threadIdx.x & 63;
  const int l15  = lane & 15;
  const int quad = lane >> 4;

  const int row_base = blockIdx.x * 256 + wave * 64;
  const int col_base = blockIdx.y * 256;

  colsum[threadIdx.x] = 0.0f;

  // A fragments: A[m=l15][k=quad*8+j]
  bf16x8 a[4][4];
  const unsigned short* abase = zn + (size_t)(row_base + l15) * DDIM + quad * 8;
  #pragma unroll
  for (int mi = 0; mi < 4; ++mi)
    #pragma unroll
    for (int kf = 0; kf < 4; ++kf)
      a[mi][kf] = *(const bf16x8*)(abase + mi * 16 * DDIM + kf * 32);

  float rs[4][4];
  #pragma unroll
  for (int mi = 0; mi < 4; ++mi)
    #pragma unroll
    for (int r = 0; r < 4; ++r) rs[mi][r] = 0.0f;

  // Staging: buffer = 32 B-rows x 16 chunks of 16B; slot t -> row t>>4,
  // chunk (t&15)^(row&15). Issues s=0,1 cover slots s*256 + wave*64 + lane.
  const int t0 = wave * 64 + lane;
  const int r0 = t0 >> 4,         c0 = (t0 & 15) ^ (r0 & 15);
  const int r1 = (t0 + 256) >> 4, c1 = (t0 & 15) ^ (r1 & 15);
  const unsigned short* gst0 = zn + (size_t)(col_base + r0) * DDIM + c0 * 8;
  const unsigned short* gst1 = zn + (size_t)(col_base + r1) * DDIM + c1 * 8;

  int rdoff[4];
  #pragma unroll
  for (int kf = 0; kf < 4; ++kf)
    rdoff[kf] = l15 * DDIM + (((quad + 4 * kf) ^ l15) << 3);

  // prime chunk 0 into buf 0
  glds16(gst0, lds + wave * 512);
  glds16(gst1, lds + 2048 + wave * 512);
  __syncthreads();

  for (int ch = 0; ch < 8; ++ch) {
    const int buf = ch & 1;
    if (ch < 7) {                                    // stage chunk ch+1
      const unsigned short* g0 = gst0 + (size_t)(ch + 1) * CHUNK * DDIM;
      const unsigned short* g1 = gst1 + (size_t)(ch + 1) * CHUNK * DDIM;
      unsigned short* lb = lds + ((ch + 1) & 1) * 4096;
      glds16(g0, lb + wave * 512);
      glds16(g1, lb + 2048 + wave * 512);
    }
    const unsigned short* lb = lds + buf * 4096;
    #pragma unroll
    for (int ni = 0; ni < 2; ++ni) {
      bf16x8 b[4];
      #pragma unroll
      for (int kf = 0; kf < 4; ++kf)
        b[kf] = *(const bf16x8*)(lb + ni * 16 * DDIM + rdoff[kf]);
      f32x4 acc[4];
      #pragma unroll
      for (int mi = 0; mi < 4; ++mi) {
        f32x4 z = {0.0f, 0.0f, 0.0f, 0.0f};
        acc[mi] = __builtin_amdgcn_mfma_f32_16x16x32_bf16(a[mi][0], b[0], z, 0, 0, 0);
      }
      #pragma unroll
      for (int kf = 1; kf < 4; ++kf)
        #pragma unroll
        for (int mi = 0; mi < 4; ++mi)
          acc[mi] = __builtin_amdgcn_mfma_f32_16x16x32_bf16(a[mi][kf], b[kf], acc[mi], 0, 0, 0);
      // e feeds this row's sum and (off-diag) the transposed row via colsum.
      float cs = 0.0f;
      #pragma unroll
      for (int mi = 0; mi < 4; ++mi)
        #pragma unroll
        for (int r = 0; r < 4; ++r) {
          float e = __builtin_amdgcn_exp2f(acc[mi][r]);
          rs[mi][r] += e;
          cs += e;
        }
      if (!diag) {
        cs += __shfl_xor(cs, 16);                    // reduce over quads
        cs += __shfl_xor(cs, 32);
        if (quad == 0)
          atomicAdd(&colsum[(ch * 2 + ni) * 16 + l15], cs);
      }
    }
    __syncthreads();                                 // drains glds + compute
  }

  // Row side. C/D layout: col=l15, row=quad*4+reg. Reduce 16 cols per quad.
  #pragma unroll
  for (int mi = 0; mi < 4; ++mi)
    #pragma unroll
    for (int r = 0; r < 4; ++r) {
      float v = rs[mi][r];
      v += __shfl_xor(v, 1);
      v += __shfl_xor(v, 2);
      v += __shfl_xor(v, 4);
      v += __shfl_xor(v, 8);
      if (l15 == 0)
        atomicAdd(&row_sums[row_base + mi * 16 + quad * 4 + r], v);
    }
  // Col side: one atomic per col per block (transposed rows).
  if (!diag)
    atomicAdd(&row_sums[col_base + threadIdx.x], colsum[threadIdx.x]);
}

// ---- Kernel 3: positives + logs + mean -----------------------------------
__global__ void finalize_kernel(const unsigned short* __restrict__ zn,
                                const float* __restrict__ row_sums,
                                float* __restrict__ out) {
  int wave = threadIdx.x >> 6;
  int lane = threadIdx.x & 63;
  int i = blockIdx.x * 4 + wave;                   // grid 1024 * 4 = 4096 pairs
  int p = i + BHALF;
  unsigned int ua = ((const unsigned int*)(zn + (size_t)i * DDIM))[lane];
  unsigned int ub = ((const unsigned int*)(zn + (size_t)p * DDIM))[lane];
  float d = __uint_as_float(ua << 16) * __uint_as_float(ub << 16)
          + __uint_as_float(ua & 0xffff0000u) * __uint_as_float(ub & 0xffff0000u);
  #pragma unroll
  for (int off = 1; off < 64; off <<= 1) d += __shfl_xor(d, off);
  // d = (2/ln2)*cos  ->  4*cos = 2ln2 * d

  __shared__ float red[4];
  if (lane == 0) {
    const float EXPDIAG = 7.38905609893065f;       // exp(2): self-similarity term
    float si = row_sums[i] - EXPDIAG;
    float sp = row_sums[p] - EXPDIAG;
    red[wave] = logf(si) + logf(sp) - TWO_LN2 * d;
  }
  __syncthreads();
  if (threadIdx.x == 0)
    atomicAdd(out, (red[0] + red[1] + red[2] + red[3]) * (1.0f / 8192.0f));
}

extern "C" void kernel_launch(void* const* d_in, const int* in_sizes, int n_in,
                              void* d_out, int out_size, void* d_ws, size_t ws_size,
                              hipStream_t stream) {
  const float* zi = (const float*)d_in[0];
  const float* zj = (const float*)d_in[1];
  unsigned short* zn = (unsigned short*)d_ws;                           // 8192*128 bf16 = 2 MB
  float* row_sums = (float*)((char*)d_ws + (size_t)NROWS * DDIM * 2);   // 8192 fp32
  float* out = (float*)d_out;

  norm_zero_kernel<<<2048, 256, 0, stream>>>(zi, zj, zn, row_sums, out);
  sim_kernel<<<dim3(32, 32), 256, 0, stream>>>(zn, row_sums);
  finalize_kernel<<<1024, 256, 0, stream>>>(zn, row_sums, out);
}